// Round 1
// baseline (42.601 us; speedup 1.0000x reference)
//
#include <hip/hip_runtime.h>
#include <hip/hip_bf16.h>

// Chamfer-style min-matching loss, B=8, P=4096, D=2, fp32.
// result = 0.5 * (mean_over[B,P](min_n d(pred_n, gt_m)) + mean_over[B,P](min_m d(pred_n, gt_m)))
// sqrt is monotone -> track min squared distance, sqrt at the end.

#define NB       8
#define NP       4096
#define PPB      256          // query points per block (== blockDim)
#define PCHUNKS  (NP / PPB)   // 16

// Kernel A: for each (dir, batch, query-chunk, base-chunk) block, compute the
// min squared distance of each of its 256 query points against the staged
// base chunk, write partial mins to ws.
template <int NC>
__global__ __launch_bounds__(256) void chamferA(const float* __restrict__ pred,
                                                const float* __restrict__ gt,
                                                float* __restrict__ ws) {
    constexpr int CHUNK = NP / NC;
    __shared__ float2 s[CHUNK];

    int bid = blockIdx.x;
    int gc  = bid % NC;      bid /= NC;
    int pc  = bid % PCHUNKS; bid /= PCHUNKS;
    int b   = bid % NB;      bid /= NB;
    int dir = bid;           // 0: query=pred, base=gt ; 1: query=gt, base=pred

    const float* query = (dir == 0) ? pred : gt;
    const float* base  = (dir == 0) ? gt   : pred;

    const float2* base2  = (const float2*)base  + (size_t)b * NP + (size_t)gc * CHUNK;
    const float2* query2 = (const float2*)query + (size_t)b * NP;

    // stage base chunk into LDS (coalesced float2 loads)
    for (int i = threadIdx.x; i < CHUNK; i += 256) s[i] = base2[i];
    __syncthreads();

    int q = pc * PPB + threadIdx.x;
    float2 qp = query2[q];
    const float px = qp.x, py = qp.y;

    float m0 = 3.402823466e+38f, m1 = m0, m2 = m0, m3 = m0;

#pragma unroll 4
    for (int j = 0; j < CHUNK; j += 4) {
        float2 g0 = s[j + 0];
        float2 g1 = s[j + 1];
        float2 g2 = s[j + 2];
        float2 g3 = s[j + 3];
        float dx, dy, d;
        dx = px - g0.x; dy = py - g0.y; d = dx * dx + dy * dy; m0 = fminf(m0, d);
        dx = px - g1.x; dy = py - g1.y; d = dx * dx + dy * dy; m1 = fminf(m1, d);
        dx = px - g2.x; dy = py - g2.y; d = dx * dx + dy * dy; m2 = fminf(m2, d);
        dx = px - g3.x; dy = py - g3.y; d = dx * dx + dy * dy; m3 = fminf(m3, d);
    }

    float mv = fminf(fminf(m0, m1), fminf(m2, m3));
    // layout: ws[((dir*NB + b)*NC + gc)*NP + q]  -> kernel B reads coalesced in q
    ws[(((size_t)dir * NB + b) * NC + gc) * NP + q] = mv;
}

// Kernel B: per point, min over chunks -> sqrt(max(.,eps)) -> block sum -> atomicAdd.
template <int NC>
__global__ __launch_bounds__(256) void chamferB(const float* __restrict__ ws,
                                                float* __restrict__ out) {
    int idx  = blockIdx.x * 256 + threadIdx.x;   // 0 .. 2*NB*NP-1 = 65535
    int dirb = idx >> 12;                        // (dir*NB + b), 0..15
    int q    = idx & (NP - 1);

    const float* p = ws + ((size_t)dirb * NC) * NP + q;
    float mv = p[0];
#pragma unroll
    for (int c = 1; c < NC; ++c) mv = fminf(mv, p[(size_t)c * NP]);

    float v = sqrtf(fmaxf(mv, 1e-12f));

    // wave (64-lane) reduction
#pragma unroll
    for (int o = 32; o > 0; o >>= 1) v += __shfl_down(v, o, 64);

    __shared__ float wsum[4];
    int lane = threadIdx.x & 63;
    int w    = threadIdx.x >> 6;
    if (lane == 0) wsum[w] = v;
    __syncthreads();
    if (threadIdx.x == 0) {
        float sblk = wsum[0] + wsum[1] + wsum[2] + wsum[3];
        atomicAdd(out, sblk * (0.5f / (float)(NB * NP)));
    }
}

extern "C" void kernel_launch(void* const* d_in, const int* in_sizes, int n_in,
                              void* d_out, int out_size, void* d_ws, size_t ws_size,
                              hipStream_t stream) {
    const float* pred = (const float*)d_in[0];
    const float* gt   = (const float*)d_in[1];
    float*       out  = (float*)d_out;
    float*       wsf  = (float*)d_ws;

    (void)in_sizes; (void)n_in; (void)out_size;

    hipMemsetAsync(d_out, 0, sizeof(float), stream);

    const size_t need8 = (size_t)2 * NB * 8 * NP * sizeof(float); // 2 MiB
    const size_t need2 = (size_t)2 * NB * 2 * NP * sizeof(float);

    if (ws_size >= need8) {
        chamferA<8><<<2 * NB * PCHUNKS * 8, 256, 0, stream>>>(pred, gt, wsf);
        chamferB<8><<<(2 * NB * NP) / 256, 256, 0, stream>>>(wsf, out);
    } else if (ws_size >= need2) {
        chamferA<2><<<2 * NB * PCHUNKS * 2, 256, 0, stream>>>(pred, gt, wsf);
        chamferB<2><<<(2 * NB * NP) / 256, 256, 0, stream>>>(wsf, out);
    } else {
        chamferA<1><<<2 * NB * PCHUNKS * 1, 256, 0, stream>>>(pred, gt, wsf);
        chamferB<1><<<(2 * NB * NP) / 256, 256, 0, stream>>>(wsf, out);
    }
}

// Round 2
// 33.559 us; speedup vs baseline: 1.2694x; 1.2694x over previous
//
#include <hip/hip_runtime.h>
#include <hip/hip_bf16.h>

// Chamfer min-matching loss, B=8, P=4096, D=2, fp32.
// d2(q, g) = |q|^2 + (|g|^2 - 2 q.g)   (same expansion the reference uses)
// Per base point precompute hx=-2gx, hy=-2gy, c=|g|^2; inner loop is then
// val = fma(px,hx, fma(py,hy,c)) -> two v_pk_fma_f32 per 2 base points,
// min3-chained. sqrt deferred to the reduce kernel (monotone).

#define NB   8
#define NP   4096
#define QPB  512                 // query points per block (2 per thread)
#define NPC  (NP / QPB)          // 8 query chunks

typedef float f32x2 __attribute__((ext_vector_type(2)));
typedef float f32x4 __attribute__((ext_vector_type(4)));

__device__ __forceinline__ f32x2 pk_fma(f32x2 a, f32x2 b, f32x2 c) {
    f32x2 d;
    asm("v_pk_fma_f32 %0, %1, %2, %3" : "=v"(d) : "v"(a), "v"(b), "v"(c));
    return d;
}

template <int NC>
__global__ __launch_bounds__(256) void chamferA(const float* __restrict__ pred,
                                                const float* __restrict__ gt,
                                                float* __restrict__ ws) {
    constexpr int CHUNK = NP / NC;
    __shared__ __align__(16) float shx[CHUNK];
    __shared__ __align__(16) float shy[CHUNK];
    __shared__ __align__(16) float sc[CHUNK];

    int bid = blockIdx.x;
    int gc  = bid % NC;        bid /= NC;
    int pc  = bid & (NPC - 1); bid >>= 3;
    int b   = bid & (NB - 1);  bid >>= 3;
    int dir = bid;             // 0: query=pred base=gt ; 1: query=gt base=pred

    const float* query = dir ? gt : pred;
    const float* base  = dir ? pred : gt;

    const float2* base2 = (const float2*)base + (size_t)b * NP + gc * CHUNK;
    int t = threadIdx.x;

    for (int i = t; i < CHUNK; i += 256) {
        float2 g = base2[i];
        shx[i] = -2.0f * g.x;
        shy[i] = -2.0f * g.y;
        sc[i]  = g.x * g.x + g.y * g.y;
    }
    __syncthreads();

    const float2* query2 = (const float2*)query + (size_t)b * NP + pc * QPB;
    float2 q0 = query2[t];
    float2 q1 = query2[t + 256];
    f32x2 px0 = {q0.x, q0.x}, py0 = {q0.y, q0.y};
    f32x2 px1 = {q1.x, q1.x}, py1 = {q1.y, q1.y};
    float p20 = q0.x * q0.x + q0.y * q0.y;
    float p21 = q1.x * q1.x + q1.y * q1.y;

    float m0 = 3.402823466e+38f, m1 = 3.402823466e+38f;

#pragma unroll 8
    for (int j = 0; j < CHUNK; j += 4) {
        f32x4 hx = *(const f32x4*)&shx[j];
        f32x4 hy = *(const f32x4*)&shy[j];
        f32x4 cc = *(const f32x4*)&sc[j];
        f32x2 hx01 = {hx.x, hx.y}, hx23 = {hx.z, hx.w};
        f32x2 hy01 = {hy.x, hy.y}, hy23 = {hy.z, hy.w};
        f32x2 c01  = {cc.x, cc.y}, c23  = {cc.z, cc.w};

        f32x2 a, v;
        a = pk_fma(py0, hy01, c01); a = pk_fma(px0, hx01, a);
        v = pk_fma(py0, hy23, c23); v = pk_fma(px0, hx23, v);
        m0 = fminf(fminf(m0, a.x), a.y);   // -> v_min3_f32
        m0 = fminf(fminf(m0, v.x), v.y);

        a = pk_fma(py1, hy01, c01); a = pk_fma(px1, hx01, a);
        v = pk_fma(py1, hy23, c23); v = pk_fma(px1, hx23, v);
        m1 = fminf(fminf(m1, a.x), a.y);
        m1 = fminf(fminf(m1, v.x), v.y);
    }

    // ws[((dir*NB + b)*NC + gc)*NP + q] ; q = pc*QPB + t (+256)
    size_t o = (((size_t)dir * NB + b) * NC + gc) * NP + pc * QPB + t;
    ws[o]       = m0 + p20;
    ws[o + 256] = m1 + p21;
}

template <int NC>
__global__ __launch_bounds__(256) void chamferB(const float* __restrict__ ws,
                                                float* __restrict__ out) {
    int idx  = blockIdx.x * 256 + threadIdx.x;   // 0 .. 2*NB*NP-1
    int dirb = idx >> 12;                        // dir*NB + b
    int q    = idx & (NP - 1);

    const float* p = ws + ((size_t)dirb * NC) * NP + q;
    float mv = p[0];
#pragma unroll
    for (int c = 1; c < NC; ++c) mv = fminf(mv, p[(size_t)c * NP]);

    float v = sqrtf(fmaxf(mv, 1e-12f));

#pragma unroll
    for (int o = 32; o > 0; o >>= 1) v += __shfl_down(v, o, 64);

    __shared__ float wsum[4];
    int lane = threadIdx.x & 63;
    int w    = threadIdx.x >> 6;
    if (lane == 0) wsum[w] = v;
    __syncthreads();
    if (threadIdx.x == 0) {
        float sblk = wsum[0] + wsum[1] + wsum[2] + wsum[3];
        atomicAdd(out, sblk * (0.5f / (float)(NB * NP)));
    }
}

extern "C" void kernel_launch(void* const* d_in, const int* in_sizes, int n_in,
                              void* d_out, int out_size, void* d_ws, size_t ws_size,
                              hipStream_t stream) {
    const float* pred = (const float*)d_in[0];
    const float* gt   = (const float*)d_in[1];
    float*       out  = (float*)d_out;
    float*       wsf  = (float*)d_ws;

    (void)in_sizes; (void)n_in; (void)out_size;

    hipMemsetAsync(d_out, 0, sizeof(float), stream);

    const size_t need16 = (size_t)2 * NB * 16 * NP * sizeof(float); // 4 MiB
    const size_t need4  = (size_t)2 * NB * 4  * NP * sizeof(float);

    if (ws_size >= need16) {
        chamferA<16><<<2 * NB * NPC * 16, 256, 0, stream>>>(pred, gt, wsf);
        chamferB<16><<<(2 * NB * NP) / 256, 256, 0, stream>>>(wsf, out);
    } else if (ws_size >= need4) {
        chamferA<4><<<2 * NB * NPC * 4, 256, 0, stream>>>(pred, gt, wsf);
        chamferB<4><<<(2 * NB * NP) / 256, 256, 0, stream>>>(wsf, out);
    } else {
        chamferA<1><<<2 * NB * NPC * 1, 256, 0, stream>>>(pred, gt, wsf);
        chamferB<1><<<(2 * NB * NP) / 256, 256, 0, stream>>>(wsf, out);
    }
}